// Round 3
// 1460.700 us; speedup vs baseline: 1.1350x; 1.1350x over previous
//
#include <hip/hip_runtime.h>

// FlowTransformerBlock on gfx950. B=2, T=2, C=128, H=W=256, PS=8, N_HEAD=1.
// ALL global I/O is FP32 (reference dtypes). Internal matmuls are bf16 MFMA.
//
// ws layout (exactly 256 MiB):
//   Qn   fp32 NHWC  2 imgs  [0,          67108864)   (attn writes Qon in-place)
//   KVn  bf16 NHWC  4 imgs  [67108864,  134217728)
//   KVwn bf16 NHWC  8 imgs  [134217728, 268435456)
// Weights (bf16, [s][o][ci], 294912 B each):
//   wtq  -> d_out bytes [0, 294912)        (d_out is dead until final conv)
//   wtkv -> d_out bytes [294912, 589824)
//   wtff -> KVwn head, prepped AFTER attn (KVwn dead by then)

typedef unsigned short u16;
typedef __attribute__((ext_vector_type(8))) __bf16 bf16x8;
typedef __attribute__((ext_vector_type(4))) float f32x4;

union F4 { float4 v; float f[4]; };
union US4 { ushort4 s; u16 u[4]; };
union V16 { int4 i4; ushort4 s4[2]; u16 u[8]; };

__device__ __forceinline__ u16 f2b(float f) {
  union { float f; unsigned u; } c; c.f = f;
  unsigned r = c.u + 0x7fffu + ((c.u >> 16) & 1u);
  return (u16)(r >> 16);
}
__device__ __forceinline__ bf16x8 ld8(const u16* p) {
  union { ushort4 s[2]; bf16x8 v; } u;
  u.s[0] = *(const ushort4*)p;
  u.s[1] = *(const ushort4*)(p + 4);
  return u.v;
}
__device__ __forceinline__ bf16x8 ld8b(const char* p) {  // 16B-aligned
  union { int4 i; bf16x8 v; } u;
  u.i = *(const int4*)p;
  return u.v;
}
// Swizzled linear layout: rows of 128 B (64 bf16), 16B slot index XOR'd with
// row&7 -> lanes reading consecutive rows at the same chunk hit 8 distinct
// bank-quads (conflict-free ds_read_b128 / ds_write_b128).
__device__ __forceinline__ int swz(int row, int chunk) {
  return row * 128 + (((chunk ^ row) & 7) << 4);
}

#define HW 65536

// ---- weight reorder: Wt[s][o][ci] (bf16) = W[o][ci][ky][kx] (fp32) --------
__global__ void prep_w(const float* __restrict__ W, u16* __restrict__ Wt) {
  int i = blockIdx.x * 256 + threadIdx.x;
  if (i >= 9 * 128 * 128) return;
  int s = i / 16384, rem = i % 16384;
  int o = rem >> 7, ci = rem & 127;
  Wt[i] = f2b(W[(o * 128 + ci) * 9 + s]);
}

// ---- conv 3x3 + bias + prelu + residual -----------------------------------
// One WG: 128 out-ch x 128 px (rows y0,y0+1, x0..x0+63). 4 waves in 2x2:
// wr = out-ch half (64), wc = output row. MFMA 16x16x32 bf16.
// x_nhwc: input layout. out_mode: 0=NCHW f32, 1=NHWC f32, 2=NHWC bf16.
__global__ __launch_bounds__(256, 3) void conv3x3_k(
    const float* __restrict__ X, const u16* __restrict__ Wt,
    const float* __restrict__ bias, const float* __restrict__ alpha,
    void* __restrict__ Out, int x_nhwc, int out_mode) {
  __shared__ __align__(16) char smem[50176];
  char* inb = smem;           // input: 264 entries (4 rows x 66 ix) x 128 B swz
  char* wb = smem + 33792;    // weights: 128 o x 128 B swz (one s, one half)
  float* o_t = (float*)smem;  // epilogue alias (mode 1): [64 px][132] f32
  u16* ob_t = (u16*)smem;     // epilogue alias (mode 2): [64 px][136] u16

  const int blk = blockIdx.x;
  const int xb = blk & 3, yb = (blk >> 2) & 127, img = blk >> 9;
  const int x0 = xb * 64, y0 = yb * 2;
  const int tid = threadIdx.x;
  const int lane = tid & 63, wv = tid >> 6;
  const int wr = wv >> 1, wc = wv & 1;
  const int quad = lane >> 4, l15 = lane & 15;

  f32x4 acc[4][4];
  const f32x4 zero4 = {0.f, 0.f, 0.f, 0.f};
#pragma unroll
  for (int i = 0; i < 4; ++i)
#pragma unroll
    for (int j = 0; j < 4; ++j) acc[i][j] = zero4;

  const float alf = alpha[0];

  for (int h = 0; h < 2; ++h) {
    __syncthreads();  // prior compute done before overwriting inb (and wb)
    if (x_nhwc) {
      // 264 entries x 8 chunks; chunk = 8 channels -> 2x float4 + b128 write
      for (int i = tid; i < 2112; i += 256) {
        int e = i >> 3, c8 = i & 7;
        int r = e / 66, ix = e - r * 66;
        int yy = y0 - 1 + r, xx = x0 - 1 + ix;
        V16 w;
        if ((unsigned)yy < 256u && (unsigned)xx < 256u) {
          const float* src = X + (((img * 256 + yy) * 256 + xx) * 128 + h * 64 + c8 * 8);
          F4 a, b2;
          a.v = *(const float4*)src;
          b2.v = *(const float4*)(src + 4);
#pragma unroll
          for (int j = 0; j < 4; ++j) {
            w.u[j] = f2b(a.f[j]);
            w.u[4 + j] = f2b(b2.f[j]);
          }
        } else {
          w.u[0] = 0; w.u[1] = 0; w.u[2] = 0; w.u[3] = 0;
          w.u[4] = 0; w.u[5] = 0; w.u[6] = 0; w.u[7] = 0;
        }
        *(int4*)(inb + swz(e, c8)) = w.i4;
      }
    } else {
      // NCHW: transpose on the READ side — lane = entry (consecutive x,
      // coalesced 4B loads), loop = channel; pack 8 ch -> one b128 write.
      // Explicit branch so no OOB address is ever dereferenced.
      for (int e = tid; e < 264; e += 256) {
        int r = e / 66, ix = e - r * 66;
        int yy = y0 - 1 + r, xx = x0 - 1 + ix;
        if ((unsigned)yy < 256u && (unsigned)xx < 256u) {
          const float* src = X + ((img * 128 + h * 64) * HW + yy * 256 + xx);
#pragma unroll
          for (int c8 = 0; c8 < 8; ++c8) {
            V16 w;
#pragma unroll
            for (int cc = 0; cc < 8; ++cc)
              w.u[cc] = f2b(src[(c8 * 8 + cc) * HW]);
            *(int4*)(inb + swz(e, c8)) = w.i4;
          }
        } else {
          V16 w;
          w.u[0] = 0; w.u[1] = 0; w.u[2] = 0; w.u[3] = 0;
          w.u[4] = 0; w.u[5] = 0; w.u[6] = 0; w.u[7] = 0;
#pragma unroll
          for (int c8 = 0; c8 < 8; ++c8)
            *(int4*)(inb + swz(e, c8)) = w.i4;
        }
      }
    }
    for (int s = 0; s < 9; ++s) {
      const int ky = s / 3, kx = s - ky * 3;
      if (s) __syncthreads();  // prior compute done before overwriting wb
      for (int i = tid; i < 1024; i += 256) {  // stage W slice half (16 KB)
        int o = i >> 3, j = i & 7;
        int4 v = *(const int4*)(Wt + (s * 16384 + o * 128 + h * 64 + j * 8));
        *(int4*)(wb + swz(o, j)) = v;
      }
      __syncthreads();  // staging visible (covers input staging at s==0)
#pragma unroll
      for (int kb = 0; kb < 2; ++kb) {
        bf16x8 af[4], bf[4];
#pragma unroll
        for (int mt = 0; mt < 4; ++mt)
          af[mt] = ld8b(wb + swz(wr * 64 + mt * 16 + l15, kb * 4 + quad));
#pragma unroll
        for (int nt = 0; nt < 4; ++nt) {
          int e = (wc + ky) * 66 + nt * 16 + l15 + kx;
          bf[nt] = ld8b(inb + swz(e, kb * 4 + quad));
        }
#pragma unroll
        for (int mt = 0; mt < 4; ++mt)
#pragma unroll
          for (int nt = 0; nt < 4; ++nt)
            acc[mt][nt] = __builtin_amdgcn_mfma_f32_16x16x32_bf16(af[mt], bf[nt], acc[mt][nt], 0, 0, 0);
      }
    }
  }
  // ---- epilogue (residual read from global fp32) ----
  __syncthreads();
  if (out_mode == 0) {
    float* Outf = (float*)Out;
    const int yy = y0 + wc;
#pragma unroll
    for (int mt = 0; mt < 4; ++mt)
#pragma unroll
      for (int nt = 0; nt < 4; ++nt)
#pragma unroll
        for (int r = 0; r < 4; ++r) {
          int ch = wr * 64 + mt * 16 + quad * 4 + r;
          int x = nt * 16 + l15;
          float xres = x_nhwc ? X[((img * 256 + yy) * 256 + x0 + x) * 128 + ch]
                              : X[(img * 128 + ch) * HW + yy * 256 + x0 + x];
          float v = acc[mt][nt][r] + bias[ch];
          v = v >= 0.f ? v : alf * v;
          Outf[(img * 128 + ch) * HW + yy * 256 + x0 + x] = v + xres;
        }
  } else if (out_mode == 1) {
    float* Outf = (float*)Out;
    for (int ph = 0; ph < 2; ++ph) {  // ph = output row within tile
      const int yy = y0 + ph;
      if (ph) __syncthreads();
      if (wc == ph) {
#pragma unroll
        for (int mt = 0; mt < 4; ++mt)
#pragma unroll
          for (int nt = 0; nt < 4; ++nt)
#pragma unroll
            for (int r = 0; r < 4; ++r) {
              int ch = wr * 64 + mt * 16 + quad * 4 + r;
              int x = nt * 16 + l15;
              float xres = x_nhwc ? X[((img * 256 + yy) * 256 + x0 + x) * 128 + ch]
                                  : X[(img * 128 + ch) * HW + yy * 256 + x0 + x];
              float v = acc[mt][nt][r] + bias[ch];
              v = v >= 0.f ? v : alf * v;
              o_t[x * 132 + ch] = v + xres;
            }
      }
      __syncthreads();
      for (int i = tid; i < 2048; i += 256) {
        int px = i >> 5, c4 = i & 31;
        float4 v = *(const float4*)&o_t[px * 132 + c4 * 4];
        *(float4*)(Outf + (((img * 256 + yy) * 256 + x0 + px) * 128 + c4 * 4)) = v;
      }
    }
  } else {
    u16* Outb = (u16*)Out;
    for (int ph = 0; ph < 2; ++ph) {
      const int yy = y0 + ph;
      if (ph) __syncthreads();
      if (wc == ph) {
#pragma unroll
        for (int mt = 0; mt < 4; ++mt)
#pragma unroll
          for (int nt = 0; nt < 4; ++nt)
#pragma unroll
            for (int r = 0; r < 4; ++r) {
              int ch = wr * 64 + mt * 16 + quad * 4 + r;
              int x = nt * 16 + l15;
              float xres = x_nhwc ? X[((img * 256 + yy) * 256 + x0 + x) * 128 + ch]
                                  : X[(img * 128 + ch) * HW + yy * 256 + x0 + x];
              float v = acc[mt][nt][r] + bias[ch];
              v = v >= 0.f ? v : alf * v;
              ob_t[x * 136 + ch] = f2b(v + xres);
            }
      }
      __syncthreads();
      for (int i = tid; i < 1024; i += 256) {
        int px = i >> 4, c8 = i & 15;
        int4 v = *(const int4*)&ob_t[px * 136 + c8 * 8];
        *(int4*)(Outb + (((img * 256 + yy) * 256 + x0 + px) * 128 + c8 * 8)) = v;
      }
    }
  }
}

// ---- windowed dual-branch attention ---------------------------------------
#define ATT_SCALE 0.08838834764831845f
#define LOG2E 1.4426950408889634f

template <int NB>  // NB = # of 64-key blocks (= T of the KV tensor)
__device__ __forceinline__ void attn_branch(
    const u16* __restrict__ kv, int b, int Y0, int X0,
    u16* kv_t, u16* p_t, const bf16x8 qf[4],
    int tid, int wv, int quad, int l15,
    f32x4 oacc[8], float lsum[4]) {
  f32x4 sacc[NB][4];
  const f32x4 zero4 = {0.f, 0.f, 0.f, 0.f};
#pragma unroll
  for (int i = 0; i < NB; ++i)
#pragma unroll
    for (int j = 0; j < 4; ++j) sacc[i][j] = zero4;

  // S = Q @ KV^T (K-dim = channels 128)
  for (int kb = 0; kb < NB; ++kb) {
    __syncthreads();
    for (int i = tid; i < 1024; i += 256) {   // [key][132] bf16
      int j = i >> 4, ch = i & 15;
      int yy = Y0 + (j >> 3), xx = X0 + (j & 7);
      int img = b * NB + kb;
      V16 v;
      v.i4 = *(const int4*)(kv + (((img * 256 + yy) * 256 + xx) * 128 + ch * 8));
      int li = j * 132 + ch * 8;
      *(ushort4*)&kv_t[li] = v.s4[0];
      *(ushort4*)&kv_t[li + 4] = v.s4[1];
    }
    __syncthreads();
#pragma unroll
    for (int kst = 0; kst < 4; ++kst) {
#pragma unroll
      for (int nt = 0; nt < 4; ++nt) {
        bf16x8 bk = ld8(&kv_t[(nt * 16 + l15) * 132 + kst * 32 + quad * 8]);
        sacc[kb][nt] = __builtin_amdgcn_mfma_f32_16x16x32_bf16(qf[kst], bk, sacc[kb][nt], 0, 0, 0);
      }
    }
  }
  // softmax (rows live across the 16 lanes of each quad)
  float mx[4];
#pragma unroll
  for (int r = 0; r < 4; ++r) {
    float m = -1e30f;
#pragma unroll
    for (int kb = 0; kb < NB; ++kb)
#pragma unroll
      for (int nt = 0; nt < 4; ++nt) m = fmaxf(m, sacc[kb][nt][r]);
    for (int d = 1; d < 16; d <<= 1) m = fmaxf(m, __shfl_xor(m, d, 64));
    mx[r] = m * ATT_SCALE;
  }
#pragma unroll
  for (int r = 0; r < 4; ++r) {
    float s = 0.f;
#pragma unroll
    for (int kb = 0; kb < NB; ++kb)
#pragma unroll
      for (int nt = 0; nt < 4; ++nt) {
        float p = exp2f((sacc[kb][nt][r] * ATT_SCALE - mx[r]) * LOG2E);
        sacc[kb][nt][r] = p;
        s += p;
      }
    for (int d = 1; d < 16; d <<= 1) s += __shfl_xor(s, d, 64);
    lsum[r] = s;
  }
  // O = P @ KV (K-dim = keys, 64/block)
#pragma unroll
  for (int i = 0; i < 8; ++i) oacc[i] = zero4;
  for (int kb = 0; kb < NB; ++kb) {
    __syncthreads();
    for (int i = tid; i < 1024; i += 256) {   // transposed KV: [d][68]
      int j = i >> 4, ch = i & 15;
      int yy = Y0 + (j >> 3), xx = X0 + (j & 7);
      int img = b * NB + kb;
      V16 v;
      v.i4 = *(const int4*)(kv + (((img * 256 + yy) * 256 + xx) * 128 + ch * 8));
#pragma unroll
      for (int cc = 0; cc < 8; ++cc) kv_t[(ch * 8 + cc) * 68 + j] = v.u[cc];
    }
#pragma unroll
    for (int nt = 0; nt < 4; ++nt)
#pragma unroll
      for (int r = 0; r < 4; ++r)
        p_t[(wv * 16 + quad * 4 + r) * 68 + nt * 16 + l15] = f2b(sacc[kb][nt][r]);
    __syncthreads();
#pragma unroll
    for (int kst = 0; kst < 2; ++kst) {
      bf16x8 ap = ld8(&p_t[(wv * 16 + l15) * 68 + kst * 32 + quad * 8]);
#pragma unroll
      for (int nt = 0; nt < 8; ++nt) {
        bf16x8 bv = ld8(&kv_t[(nt * 16 + l15) * 68 + kst * 32 + quad * 8]);
        oacc[nt] = __builtin_amdgcn_mfma_f32_16x16x32_bf16(ap, bv, oacc[nt], 0, 0, 0);
      }
    }
  }
}

__global__ __launch_bounds__(256, 2) void attn_k(
    float* __restrict__ Qn,                 // fp32 NHWC, updated IN-PLACE
    const u16* __restrict__ KVn, const u16* __restrict__ KVwn,
    const float* __restrict__ em) {
  __shared__ __align__(16) u16 q_t[64 * 132];   // Q window bf16 [q][d]
  __shared__ __align__(16) u16 kv_t[128 * 68];  // [key][132] or [d][68]
  __shared__ __align__(16) u16 p_t[64 * 68];    // P [q][key]

  const int wi = blockIdx.x;
  const int b = wi >> 10, wy = (wi >> 5) & 31, wx = wi & 31;
  const int Y0 = wy * 8, X0 = wx * 8;
  const int tid = threadIdx.x, lane = tid & 63, wv = tid >> 6;
  const int quad = lane >> 4, l15 = lane & 15;

  for (int i = tid; i < 2048; i += 256) {   // stage Q window fp32->bf16
    int qq = i >> 5, c4 = i & 31;
    int yy = Y0 + (qq >> 3), xx = X0 + (qq & 7);
    F4 v;
    v.v = *(const float4*)(Qn + (((b * 256 + yy) * 256 + xx) * 128 + c4 * 4));
    US4 s;
#pragma unroll
    for (int j = 0; j < 4; ++j) s.u[j] = f2b(v.f[j]);
    *(ushort4*)&q_t[qq * 132 + c4 * 4] = s.s;
  }
  float mval[4];
#pragma unroll
  for (int r = 0; r < 4; ++r) {
    int q = wv * 16 + quad * 4 + r;
    mval[r] = em[b * 65536 + (Y0 + (q >> 3)) * 256 + X0 + (q & 7)];
  }
  __syncthreads();
  bf16x8 qf[4];
#pragma unroll
  for (int kst = 0; kst < 4; ++kst)
    qf[kst] = ld8(&q_t[(wv * 16 + l15) * 132 + kst * 32 + quad * 8]);

  f32x4 o1[8], o2[8];
  float l1[4], l2[4];
  attn_branch<2>(KVn, b, Y0, X0, kv_t, p_t, qf, tid, wv, quad, l15, o1, l1);
  attn_branch<4>(KVwn, b, Y0, X0, kv_t, p_t, qf, tid, wv, quad, l15, o2, l2);

#pragma unroll
  for (int r = 0; r < 4; ++r) { l1[r] = 1.f / l1[r]; l2[r] = 1.f / l2[r]; }
#pragma unroll
  for (int nt = 0; nt < 8; ++nt) {
#pragma unroll
    for (int r = 0; r < 4; ++r) {
      int q = wv * 16 + quad * 4 + r;
      int c = nt * 16 + l15;
      int gi = ((b * 256 + Y0 + (q >> 3)) * 256 + X0 + (q & 7)) * 128 + c;
      float v = mval[r] * (o1[nt][r] * l1[r]) + (1.f - mval[r]) * (o2[nt][r] * l2[r]);
      v += Qn[gi];             // shortcut (read fp32, then overwrite in-place)
      Qn[gi] = v;
    }
  }
}

// ---------------------------------------------------------------------------
extern "C" void kernel_launch(void* const* d_in, const int* in_sizes, int n_in,
                              void* d_out, int out_size, void* d_ws, size_t ws_size,
                              hipStream_t stream) {
  (void)in_sizes; (void)n_in; (void)out_size; (void)ws_size;
  const float* xq   = (const float*)d_in[0];
  const float* xkvw = (const float*)d_in[1];
  const float* xkv  = (const float*)d_in[2];
  const float* em   = (const float*)d_in[3];
  const float* Wq   = (const float*)d_in[4];
  const float* bq   = (const float*)d_in[5];
  const float* aq   = (const float*)d_in[6];
  const float* Wkv  = (const float*)d_in[7];
  const float* bkv  = (const float*)d_in[8];
  const float* akv  = (const float*)d_in[9];
  const float* Wff  = (const float*)d_in[10];
  const float* bff  = (const float*)d_in[11];
  const float* aff  = (const float*)d_in[12];

  char* ws = (char*)d_ws;
  float* Qn = (float*)ws;                       // 67,108,864 B
  u16* KVn  = (u16*)(ws + 67108864);            // 67,108,864 B
  u16* KVwn = (u16*)(ws + 134217728);           // 134,217,728 B
  u16* wtq  = (u16*)d_out;                      // dead region until final conv
  u16* wtkv = (u16*)d_out + 147456;
  u16* wtff = KVwn;                             // KVwn dead after attn

  prep_w<<<576, 256, 0, stream>>>(Wq, wtq);
  prep_w<<<576, 256, 0, stream>>>(Wkv, wtkv);

  conv3x3_k<<<1024, 256, 0, stream>>>(xq,   wtq,  bq,  aq,  Qn,   0, 1);
  conv3x3_k<<<2048, 256, 0, stream>>>(xkv,  wtkv, bkv, akv, KVn,  0, 2);
  conv3x3_k<<<4096, 256, 0, stream>>>(xkvw, wtkv, bkv, akv, KVwn, 0, 2);

  attn_k<<<2048, 256, 0, stream>>>(Qn, KVn, KVwn, em);

  prep_w<<<576, 256, 0, stream>>>(Wff, wtff);
  conv3x3_k<<<1024, 256, 0, stream>>>(Qn, wtff, bff, aff, d_out, 1, 0);
}